// Round 8
// baseline (159.832 us; speedup 1.0000x reference)
//
#include <hip/hip_runtime.h>

typedef unsigned short u16;
typedef unsigned int u32;

typedef __bf16 bf16x8 __attribute__((ext_vector_type(8)));
typedef float floatx4 __attribute__((ext_vector_type(4)));

// ---- helpers ----------------------------------------------------------------

__device__ __forceinline__ u32 f2bf(float f) {
    // round-to-nearest-even fp32 -> bf16 (bit pattern in low 16)
    u32 u = __builtin_bit_cast(u32, f);
    return (u + 0x7fffu + ((u >> 16) & 1u)) >> 16;
}

__device__ __forceinline__ float quant_w(float x) {
    // WAGE Quantize.W, BITS_W=2: clip to [-0.5,0.5], round to grid step 0.5 (RNE)
    float xc = fminf(fmaxf(x, -0.5f), 0.5f);
    return rintf(xc * 2.0f) * 0.5f;
}

__device__ __forceinline__ void gload_lds16(const u16* g, u16* l) {
    __builtin_amdgcn_global_load_lds(
        (const __attribute__((address_space(1))) void*)g,
        (__attribute__((address_space(3))) void*)l,
        16, 0, 0);
}

// ---- kernel 1: cast A fp32 -> bf16 (16 floats / thread) ---------------------

__global__ __launch_bounds__(256) void cast_a_kernel(const float4* __restrict__ in,
                                                     uint4* __restrict__ out) {
    int t = blockIdx.x * 256 + threadIdx.x;  // 4096 blocks, 64B read / 32B write each
#pragma unroll
    for (int u = 0; u < 2; u++) {
        float4 a = in[4 * t + 2 * u];
        float4 b = in[4 * t + 2 * u + 1];
        uint4 o;
        o.x = f2bf(a.x) | (f2bf(a.y) << 16);
        o.y = f2bf(a.z) | (f2bf(a.w) << 16);
        o.z = f2bf(b.x) | (f2bf(b.y) << 16);
        o.w = f2bf(b.z) | (f2bf(b.w) << 16);
        out[2 * t + u] = o;
    }
}

// ---- kernel 2: quantize + transpose W[k][n] -> Bt[n][k] bf16 ----------------

__global__ __launch_bounds__(256) void quant_transpose_kernel(const float* __restrict__ W,
                                                              u16* __restrict__ Bt) {
    __shared__ u16 tile[32][33];  // +1 pad: no bank conflicts
    const int KN = 1024;
    int tx = threadIdx.x;  // 0..31
    int ty = threadIdx.y;  // 0..7
    int k0 = blockIdx.y * 32;
    int n0 = blockIdx.x * 32;
#pragma unroll
    for (int i = 0; i < 4; i++) {
        int kl = ty + i * 8;
        float x = W[(k0 + kl) * KN + n0 + tx];
        tile[kl][tx] = (u16)f2bf(quant_w(x));
    }
    __syncthreads();
#pragma unroll
    for (int i = 0; i < 4; i++) {
        int nl = ty + i * 8;
        Bt[(n0 + nl) * KN + k0 + tx] = tile[tx][nl];
    }
}

// ---- kernel 3: 128x128 high-occupancy pipelined GEMM  C = A(bf16)*Bt^T ------
// R3/R5/R6/R7 (1 x 512-thr block/CU, 128 KB LDS) all plateau at 42-48us,
// MfmaUtil 26-30%, across 4 different sync structures => the limiter is that
// a single barrier-locked block leaves the CU idle at every sync. R8 attacks
// occupancy: 256 thr (4 waves, 2Mx2N), BK=32, LDS 32 KB -> 4 blocks/CU
// (16 waves/CU, 4/SIMD). Independent blocks phase-shift and hide each
// other's vmcnt/lgkm/barrier stalls.
//
// One region per K-tile (32 tiles), ONE barrier each:
//   stage(t+1) x4 DMA  ->  MFMA(t-1) x16 (operands drained last region ->
//   issues immediately)  ->  vmcnt(4)  ->  ds_read af(t),bf(t) x8  ->
//   lgkmcnt(0)  ->  barrier
// WAR: stage(t+1) writes buf b^1; its last readers (tile t-1's ds_reads) were
//   lgkm(0)-drained before region(t-1)'s barrier -> chip-wide safe.
// RAW: vmcnt(4) drains exactly tile-t's 4 DMAs (issued one region earlier),
//   keeps tile-t+1's 4 in flight; vmcnt(0) only at t=31.
// Reg dbuf (rule #20): loop unrolled x2 with named sets afA/bfA, afB/bfB.
// Swizzle (BK=32, 64 B rows): chunk' = chunk ^ ((row>>1)&3) gives exactly
//   2-way bank aliasing on ds_read_b128 (free per m136); gload_lds dest
//   stays linear, global source pre-swizzled.
// Accumulation: 32 ascending k-chunks per acc element -> bitwise-identical
//   to the verified R5/R7 kernels.

__global__ __launch_bounds__(256, 4) void gemm_occ_kernel(const u16* __restrict__ A,
                                                          const u16* __restrict__ Bt,
                                                          float* __restrict__ C) {
    const int K = 1024;
    const int N = 1024;

    __shared__ alignas(16) u16 As[2][128][32];  // 16 KB
    __shared__ alignas(16) u16 Bs[2][128][32];  // 16 KB

    const int tid = threadIdx.x;
    const int lane = tid & 63;
    const int wid = tid >> 6;     // 0..3
    const int wm = wid >> 1;      // M half (64 rows)
    const int wn = wid & 1;       // N half (64 cols)
    const int frow = lane & 15;
    const int fkc = lane >> 4;    // k-chunk 0..3
    const int mbase = blockIdx.x * 128;
    const int nbase = blockIdx.y * 128;

    // staging map: thread t -> row t>>2 (+u*64), chunk t&3, swizzled global chunk
    const int sr = tid >> 2;      // 0..63
    const int sc = tid & 3;

    floatx4 acc[4][4] = {};
    bf16x8 afA[4], bfA[4], afB[4], bfB[4];

    auto stageA = [&](int tau, int u) {
        const int r = u * 64 + sr;
        const int gcc = sc ^ ((r >> 1) & 3);
        gload_lds16(&A[(size_t)(mbase + r) * K + (size_t)tau * 32 + gcc * 8],
                    &As[tau & 1][r][sc * 8]);
    };
    auto stageB = [&](int tau, int u) {
        const int r = u * 64 + sr;
        const int gcc = sc ^ ((r >> 1) & 3);
        gload_lds16(&Bt[(size_t)(nbase + r) * K + (size_t)tau * 32 + gcc * 8],
                    &Bs[tau & 1][r][sc * 8]);
    };

#define LGKM0() asm volatile("s_waitcnt lgkmcnt(0)" ::: "memory")
#define VMC(n)  asm volatile("s_waitcnt vmcnt(" #n ")" ::: "memory")
#define BAR()                          \
    __builtin_amdgcn_sched_barrier(0); \
    __builtin_amdgcn_s_barrier();      \
    __builtin_amdgcn_sched_barrier(0)

#define READS(AF, BF, b)                                                             \
    _Pragma("unroll") for (int mf = 0; mf < 4; mf++) {                               \
        const int r = wm * 64 + mf * 16 + frow;                                      \
        AF[mf] = *(const bf16x8*)&As[b][r][(fkc ^ ((r >> 1) & 3)) * 8];              \
    }                                                                                \
    _Pragma("unroll") for (int nf = 0; nf < 4; nf++) {                               \
        const int r = wn * 64 + nf * 16 + frow;                                      \
        BF[nf] = *(const bf16x8*)&Bs[b][r][(fkc ^ ((r >> 1) & 3)) * 8];              \
    }

#define MFMA_CL(AF, BF)                                                              \
    __builtin_amdgcn_s_setprio(1);                                                   \
    _Pragma("unroll") for (int mf = 0; mf < 4; mf++)                                 \
        _Pragma("unroll") for (int nf = 0; nf < 4; nf++)                             \
            acc[mf][nf] = __builtin_amdgcn_mfma_f32_16x16x32_bf16(                   \
                AF[mf], BF[nf], acc[mf][nf], 0, 0, 0);                               \
    __builtin_amdgcn_s_setprio(0)

#define REGION(tt, AFP, BFP, AFC, BFC, DOM, DOS, VN)                                 \
    do {                                                                             \
        if (DOS) { stageA((tt) + 1, 0); stageA((tt) + 1, 1);                         \
                   stageB((tt) + 1, 0); stageB((tt) + 1, 1); }                       \
        __builtin_amdgcn_sched_barrier(0);                                           \
        if (DOM) { MFMA_CL(AFP, BFP); }                                              \
        __builtin_amdgcn_sched_barrier(0);                                           \
        VMC(VN);                                                                     \
        READS(AFC, BFC, (tt) & 1)                                                    \
        LGKM0();                                                                     \
        BAR();                                                                       \
    } while (0)

    // ---- prologue: stage tile 0 ----
    stageA(0, 0); stageA(0, 1); stageB(0, 0); stageB(0, 1);

    // region 0: no MFMA; stage tile 1; land tile 0; read set A
    REGION(0, afA, bfA, afA, bfA, false, true, 4);

    // steady: t = 1..30, unrolled x2 for register set alternation
    for (int t = 1; t < 31; t += 2) {
        REGION(t,     afA, bfA, afB, bfB, true, true, 4);   // MFMA(t-1,set0), read set1
        REGION(t + 1, afB, bfB, afA, bfA, true, true, 4);   // MFMA(t,  set1), read set0
    }

    // region 31: MFMA(30,set0); no stage; land tile 31; read set1
    REGION(31, afA, bfA, afB, bfB, true, false, 0);

    // epilogue MFMA: tile 31 (set1)
    MFMA_CL(afB, bfB);

#undef LGKM0
#undef VMC
#undef BAR
#undef READS
#undef MFMA_CL
#undef REGION

    // epilogue: C/D layout col = lane&15, row = (lane>>4)*4 + reg
    const int crow = (lane >> 4) * 4;
    const int ccol = lane & 15;
#pragma unroll
    for (int i = 0; i < 4; i++) {
#pragma unroll
        for (int j = 0; j < 4; j++) {
            float* cp = &C[(size_t)(mbase + wm * 64 + i * 16 + crow) * N +
                           nbase + wn * 64 + j * 16 + ccol];
#pragma unroll
            for (int r = 0; r < 4; r++) cp[r * N] = acc[i][j][r];
        }
    }
}

// ---- launch -----------------------------------------------------------------

extern "C" void kernel_launch(void* const* d_in, const int* in_sizes, int n_in,
                              void* d_out, int out_size, void* d_ws, size_t ws_size,
                              hipStream_t stream) {
    const float* A = (const float*)d_in[0];   // 16384 x 1024 fp32
    const float* W = (const float*)d_in[1];   // 1024 x 1024 fp32
    float* C = (float*)d_out;                 // 16384 x 1024 fp32

    u16* Abf = (u16*)d_ws;                                   // 32 MB bf16 A
    u16* Btq = (u16*)((char*)d_ws + (size_t)33554432);       // 2 MB quantized W^T

    cast_a_kernel<<<4096, 256, 0, stream>>>((const float4*)A, (uint4*)Abf);
    quant_transpose_kernel<<<dim3(32, 32), dim3(32, 8), 0, stream>>>(W, Btq);
    gemm_occ_kernel<<<dim3(128, 8), 256, 0, stream>>>(Abf, Btq, C);
}

// Round 9
// 147.619 us; speedup vs baseline: 1.0827x; 1.0827x over previous
//
#include <hip/hip_runtime.h>

typedef unsigned short u16;
typedef unsigned int u32;

typedef __bf16 bf16x8 __attribute__((ext_vector_type(8)));
typedef float floatx4 __attribute__((ext_vector_type(4)));

// ---- helpers ----------------------------------------------------------------

__device__ __forceinline__ u32 f2bf(float f) {
    // round-to-nearest-even fp32 -> bf16 (bit pattern in low 16)
    u32 u = __builtin_bit_cast(u32, f);
    return (u + 0x7fffu + ((u >> 16) & 1u)) >> 16;
}

__device__ __forceinline__ float quant_w(float x) {
    // WAGE Quantize.W, BITS_W=2: clip to [-0.5,0.5], round to grid step 0.5 (RNE)
    float xc = fminf(fmaxf(x, -0.5f), 0.5f);
    return rintf(xc * 2.0f) * 0.5f;
}

__device__ __forceinline__ void gload_lds16(const u16* g, u16* l) {
    __builtin_amdgcn_global_load_lds(
        (const __attribute__((address_space(1))) void*)g,
        (__attribute__((address_space(3))) void*)l,
        16, 0, 0);
}

// ---- kernel 1: cast A fp32 -> bf16 (16 floats / thread) ---------------------

__global__ __launch_bounds__(256) void cast_a_kernel(const float4* __restrict__ in,
                                                     uint4* __restrict__ out) {
    int t = blockIdx.x * 256 + threadIdx.x;  // 4096 blocks
#pragma unroll
    for (int u = 0; u < 2; u++) {
        float4 a = in[4 * t + 2 * u];
        float4 b = in[4 * t + 2 * u + 1];
        uint4 o;
        o.x = f2bf(a.x) | (f2bf(a.y) << 16);
        o.y = f2bf(a.z) | (f2bf(a.w) << 16);
        o.z = f2bf(b.x) | (f2bf(b.y) << 16);
        o.w = f2bf(b.z) | (f2bf(b.w) << 16);
        out[2 * t + u] = o;
    }
}

// ---- kernel 2: quantize + transpose W[k][n] -> Bt[n][k] bf16 ----------------

__global__ __launch_bounds__(256) void quant_transpose_kernel(const float* __restrict__ W,
                                                              u16* __restrict__ Bt) {
    __shared__ u16 tile[32][33];  // +1 pad: no bank conflicts
    const int KN = 1024;
    int tx = threadIdx.x;  // 0..31
    int ty = threadIdx.y;  // 0..7
    int k0 = blockIdx.y * 32;
    int n0 = blockIdx.x * 32;
#pragma unroll
    for (int i = 0; i < 4; i++) {
        int kl = ty + i * 8;
        float x = W[(k0 + kl) * KN + n0 + tx];
        tile[kl][tx] = (u16)f2bf(quant_w(x));
    }
    __syncthreads();
#pragma unroll
    for (int i = 0; i < 4; i++) {
        int nl = ty + i * 8;
        Bt[(n0 + nl) * KN + k0 + tx] = tile[tx][nl];
    }
}

// ---- kernel 3: 256x256 8-phase GEMM, bare barriers (m141 lesson) ------------
// Geometry identical to the verified R3/R5 kernels (512 thr = 8 waves 2Mx4N,
// BK=64, LDS 128 KB 2-dbuf, 16 MFMA/phase, same per-acc accumulation order ->
// bitwise-identical C). Fencing reduced to the provable minimum: ONE
// "memory"-clobbered waitcnt per phase + bare s_barrier. NO sched_barrier(0)
// anywhere -> MFMAs/VALU (register-only) float across barriers; the compiler
// interleaves phase-P MFMA with phase-P+1 ds_reads (m141: pinning this
// costs -42%).
//
// Hoist-tolerant WAR ledger: a memory op may drift up to the previous
// clobber. Passing bar2(Q) implies all waves passed CLOB(Q) (their reads
// <= phase Q drained). Rule: slot staged in phase P has last reader in
// phase <= P-2:
//   q0(t): read af0,bf0 | stage Bu1(t+1)  [last read bf1@q1(t-1), gap 3]
//   q1(t): read bf1     | stage Ahi(t+1)  [last read af1@q2(t-1), gap 3]
//   q2(t): read af1     | stage Alo(t+2)  [last read af0@q0(t),   gap 2]
//   q3(t): --           | stage Bu0(t+2)  [last read bf0@q0(t),   gap 3]
// Units (2 gloads each, per-wave rows linear): Alo/Ahi = A rows 0-63/64-127
// per M-half slot; Bu0 = B rows {0-31,64-95} (bf0), Bu1 = {32-63,96-127}
// (bf1) per N-half slot.
// RAW (vmcnt, clobbers keep counts exact; 2 units = 4 ops in flight):
//   steady q3(t): outstanding 12 ops -> vmcnt(4) drains exactly tile t+1,
//   leaves Alo/Bu0(t+2). Prologue: Alo0,Bu00,Bu10,Ahi0,Alo1,Bu01; vmcnt(4).
//   t=14: vmcnt(0). Reads@q0(t) hoist-limit = post-q3(t-1)-vmcnt = exactly
//   where tile t is guaranteed landed.

__global__ __launch_bounds__(512, 2) void gemm_8phase_v2_kernel(const u16* __restrict__ A,
                                                                const u16* __restrict__ Bt,
                                                                float* __restrict__ C) {
    const int K = 1024;
    const int N = 1024;

    __shared__ alignas(16) u16 As[2 * 2 * 128 * 64];  // 64 KB
    __shared__ alignas(16) u16 Bs[2 * 2 * 128 * 64];  // 64 KB

    const int tid = threadIdx.x;
    const int lane = tid & 63;
    const int wid = tid >> 6;
    const int wm = wid >> 2;      // M half (128 rows)
    const int wn = wid & 3;       // N quarter (64 cols)
    const int frow = lane & 15;
    const int fkc = lane >> 4;
    const int rsw = frow & 7;
    const int mbase = blockIdx.x * 256;
    const int nbase = blockIdx.y * 256;

    const int sr = tid >> 3;              // 0..63 staging row
    const int gc = (tid & 7) ^ (sr & 7);  // swizzled global k-chunk
    const int brow0 = ((sr >> 5) << 6) | (sr & 31);  // B u-remap base

    floatx4 acc[8][4] = {};
    bf16x8 af0[4][2], af1[4][2], bf0[2][2], bf1[2][2];

    // A unit u: rows u*64 + 0..63 of each M-half slot (2 gloads)
    auto astage = [&](int tau, int u) {
        const int r = u * 64 + sr;
#pragma unroll
        for (int hf = 0; hf < 2; hf++) {
            const u16* g = &A[(size_t)(mbase + hf * 128 + r) * K + (size_t)tau * 64 + gc * 8];
            u16* dst = &As[(((tau & 1) * 2 + hf) * 8192) + r * 64 + (tid & 7) * 8];
            gload_lds16(g, dst);
        }
    };
    // B unit u: rows brow0 + u*32 of each N-half slot (2 gloads)
    auto bstage = [&](int tau, int u) {
        const int r = brow0 + u * 32;
#pragma unroll
        for (int hf = 0; hf < 2; hf++) {
            const u16* g = &Bt[(size_t)(nbase + hf * 128 + r) * K + (size_t)tau * 64 + gc * 8];
            u16* dst = &Bs[(((tau & 1) * 2 + hf) * 8192) + r * 64 + (tid & 7) * 8];
            gload_lds16(g, dst);
        }
    };

#define CLOB_LGKM() asm volatile("s_waitcnt lgkmcnt(0)" ::: "memory")
#define CLOB_VM(n)  asm volatile("s_waitcnt vmcnt(" #n ")" ::: "memory")
#define SB()        __builtin_amdgcn_s_barrier()

#define READ_AF0(b)                                                                  \
    _Pragma("unroll") for (int mf = 0; mf < 4; mf++)                                 \
        _Pragma("unroll") for (int s = 0; s < 2; s++)                                \
            af0[mf][s] = *(const bf16x8*)&As[(((b)*2 + wm) * 128 + mf * 16 + frow) * 64 + \
                                             (((s * 4 + fkc) ^ rsw) * 8)]
#define READ_AF1(b)                                                                  \
    _Pragma("unroll") for (int mf = 0; mf < 4; mf++)                                 \
        _Pragma("unroll") for (int s = 0; s < 2; s++)                                \
            af1[mf][s] = *(const bf16x8*)&As[(((b)*2 + wm) * 128 + 64 + mf * 16 + frow) * 64 + \
                                             (((s * 4 + fkc) ^ rsw) * 8)]
#define READ_BF0(b)                                                                  \
    _Pragma("unroll") for (int nf = 0; nf < 2; nf++)                                 \
        _Pragma("unroll") for (int s = 0; s < 2; s++)                                \
            bf0[nf][s] = *(const bf16x8*)&Bs[(((b)*2 + (wn >> 1)) * 128 + (wn & 1) * 64 + nf * 16 + frow) * 64 + \
                                             (((s * 4 + fkc) ^ rsw) * 8)]
#define READ_BF1(b)                                                                  \
    _Pragma("unroll") for (int nf = 0; nf < 2; nf++)                                 \
        _Pragma("unroll") for (int s = 0; s < 2; s++)                                \
            bf1[nf][s] = *(const bf16x8*)&Bs[(((b)*2 + (wn >> 1)) * 128 + (wn & 1) * 64 + 32 + nf * 16 + frow) * 64 + \
                                             (((s * 4 + fkc) ^ rsw) * 8)]
#define MFMA_CL(af, bf, mo, no)                                                      \
    __builtin_amdgcn_s_setprio(1);                                                   \
    _Pragma("unroll") for (int mf = 0; mf < 4; mf++)                                 \
        _Pragma("unroll") for (int nf = 0; nf < 2; nf++)                             \
            _Pragma("unroll") for (int s = 0; s < 2; s++)                            \
                acc[(mo) + mf][(no) + nf] = __builtin_amdgcn_mfma_f32_16x16x32_bf16( \
                    af[mf][s], bf[nf][s], acc[(mo) + mf][(no) + nf], 0, 0, 0);       \
    __builtin_amdgcn_s_setprio(0)

    // ---- prologue: Alo0,Bu00,Bu10,Ahi0,Alo1,Bu01 (12 ops); land tile 0 ----
    astage(0, 0); bstage(0, 0); bstage(0, 1); astage(0, 1);
    astage(1, 0); bstage(1, 0);
    CLOB_VM(4);
    SB();

    for (int t = 0; t < 16; t++) {
        const int b = t & 1;

        // ---- q0: read af0,bf0(t) | stage Bu1(t+1) ----
        READ_AF0(b);
        READ_BF0(b);
        if (t <= 14) bstage(t + 1, 1);
        CLOB_LGKM();
        SB();
        MFMA_CL(af0, bf0, 0, 0);
        SB();

        // ---- q1: read bf1(t) | stage Ahi(t+1) ----
        READ_BF1(b);
        if (t <= 14) astage(t + 1, 1);
        CLOB_LGKM();
        SB();
        MFMA_CL(af0, bf1, 0, 2);
        SB();

        // ---- q2: read af1(t) | stage Alo(t+2) ----
        READ_AF1(b);
        if (t <= 13) astage(t + 2, 0);
        CLOB_LGKM();
        SB();
        MFMA_CL(af1, bf0, 4, 0);
        SB();

        // ---- q3: stage Bu0(t+2) | counted vmcnt ----
        if (t <= 13) {
            bstage(t + 2, 0);
            CLOB_VM(4);
        } else if (t == 14) {
            CLOB_VM(0);
        }
        SB();
        MFMA_CL(af1, bf1, 4, 2);
        SB();
    }

#undef CLOB_LGKM
#undef CLOB_VM
#undef SB
#undef READ_AF0
#undef READ_AF1
#undef READ_BF0
#undef READ_BF1
#undef MFMA_CL

    // epilogue: C/D layout col = lane&15, row = (lane>>4)*4 + reg
    const int crow = (lane >> 4) * 4;
    const int ccol = lane & 15;
#pragma unroll
    for (int i = 0; i < 8; i++) {
#pragma unroll
        for (int j = 0; j < 4; j++) {
            float* cp = &C[(size_t)(mbase + wm * 128 + i * 16 + crow) * N +
                           nbase + wn * 64 + j * 16 + ccol];
#pragma unroll
            for (int r = 0; r < 4; r++) cp[r * N] = acc[i][j][r];
        }
    }
}

// ---- launch -----------------------------------------------------------------

extern "C" void kernel_launch(void* const* d_in, const int* in_sizes, int n_in,
                              void* d_out, int out_size, void* d_ws, size_t ws_size,
                              hipStream_t stream) {
    const float* A = (const float*)d_in[0];   // 16384 x 1024 fp32
    const float* W = (const float*)d_in[1];   // 1024 x 1024 fp32
    float* C = (float*)d_out;                 // 16384 x 1024 fp32

    u16* Abf = (u16*)d_ws;                                   // 32 MB bf16 A
    u16* Btq = (u16*)((char*)d_ws + (size_t)33554432);       // 2 MB quantized W^T

    cast_a_kernel<<<4096, 256, 0, stream>>>((const float4*)A, (uint4*)Abf);
    quant_transpose_kernel<<<dim3(32, 32), dim3(32, 8), 0, stream>>>(W, Btq);
    gemm_8phase_v2_kernel<<<dim3(64, 4), 512, 0, stream>>>(Abf, Btq, C);
}